// Round 9
// baseline (677.993 us; speedup 1.0000x reference)
//
#include <hip/hip_runtime.h>
#include <cfloat>
#include <cmath>

#define NEG_SLOPE 0.01f
#define S_EMPTY 0x007FFFFFu   // sortable(-inf): empty-segment sentinel

typedef __attribute__((ext_vector_type(8))) short short8;
typedef __attribute__((ext_vector_type(4))) float f32x4;

__device__ __forceinline__ float lrelu(float v) { return v >= 0.0f ? v : NEG_SLOPE * v; }

// f32 -> bf16 round-to-nearest-even (monotone; identity on exact bf16 values)
__device__ __forceinline__ ushort f2b(float f) {
    unsigned u = __float_as_uint(f);
    u += 0x7fffu + ((u >> 16) & 1u);
    return (ushort)(u >> 16);
}
__device__ __forceinline__ float b2f(ushort s) { return __uint_as_float(((unsigned)s) << 16); }

// order-preserving f32-bits -> uint map: integer max == float max
__device__ __forceinline__ uint sortable(uint u) {
    return u ^ (uint)(((int)u >> 31) | 0x80000000);
}

// split 8 consecutive f32 into hi/lo bf16 fragments (register-resident)
__device__ __forceinline__ void split8(const float* v, short8& hi, short8& lo) {
#pragma unroll
    for (int j = 0; j < 8; ++j) {
        ushort h = f2b(v[j]);
        hi[j] = (short)h;
        lo[j] = (short)f2b(v[j] - b2f(h));
    }
}

// ---- dispatch 0: weight transpose (f32 -> bf16) + aggU sentinel init -------
// grid MUST be exactly 256 blocks x 256 threads.
// WT[mat][n*128+k]; mat 0=Wh1, 1=Wfx (Wf rows 3..130), 2=Wg1, 3=Wg2.
__global__ __launch_bounds__(256) void wprep_kernel(
    const float* __restrict__ Wh1, const float* __restrict__ Wf,
    const float* __restrict__ Wg1, const float* __restrict__ Wg2,
    ushort* __restrict__ WT, uint* __restrict__ aggU, int M)
{
    int tt = blockIdx.x * 256 + threadIdx.x;   // 0..65535
    {
        int mat = tt >> 14;
        int idx = tt & 16383;
        int n = idx >> 7, k = idx & 127;
        float v;
        if (mat == 0)      v = Wh1[k * 128 + n];
        else if (mat == 1) v = Wf[(k + 3) * 128 + n];
        else if (mat == 2) v = Wg1[k * 128 + n];
        else               v = Wg2[k * 128 + n];
        WT[(tt - idx) + n * 128 + k] = f2b(v);
    }
    // sentinel-init the aggregation plane (M*128 uints, /4 for uint4)
    uint4* p = (uint4*)aggU;
    int n4 = (M * 128) >> 2;
    uint4 sv = make_uint4(S_EMPTY, S_EMPTY, S_EMPTY, S_EMPTY);
    for (int i = tt; i < n4; i += 65536) p[i] = sv;
}

// ---------------- MFMA GEMM skeleton ----------------
// block = 256 thr = 4 waves; tile 64 rows x 128 cols; K = 128 (4 steps of 32).
// wave w covers rows [w*16, w*16+16); lane: qd = L>>4, ln = L&15.
// A-operand in registers (hi/lo split, 2 MFMAs per fragment).
// b_frag: Bs[n = nt*16+ln][k = ks*32+qd*8+j]  (LDS, stride 136 bf16)
// D:      C[m = w*16+qd*4+r][n = nt*16+ln] = acc[nt][r]

#define GEMM_CORE_REG(ACC, AH, AL)                                              \
    {                                                                           \
        _Pragma("unroll")                                                       \
        for (int ks = 0; ks < 4; ++ks) {                                        \
            _Pragma("unroll")                                                   \
            for (int nt = 0; nt < 8; ++nt) {                                    \
                short8 bfr = *(const short8*)&Bs[(nt * 16 + ln) * 136 + ks * 32 + qd * 8]; \
                ACC[nt] = __builtin_amdgcn_mfma_f32_16x16x32_bf16(AL[ks], bfr, ACC[nt], 0, 0, 0); \
                ACC[nt] = __builtin_amdgcn_mfma_f32_16x16x32_bf16(AH[ks], bfr, ACC[nt], 0, 0, 0); \
            }                                                                   \
        }                                                                       \
    }

// stage B from pre-transposed bf16 WT (layout WT[n*128+k]); coalesced uint4
#define STAGE_B(WTP)                                                            \
    {                                                                           \
        _Pragma("unroll")                                                       \
        for (int i = 0; i < 8; ++i) {                                           \
            int c = tid + 256 * i;                                              \
            int r = c >> 4, col8 = (c & 15) * 8;                                \
            *(uint4*)&Bs[r * 136 + col8] = *(const uint4*)((WTP) + r * 128 + col8); \
        }                                                                       \
    }

// ---- dispatch 1: hy  (h1=lrelu(x@Wh1+bh1); q=tanh(h1@Wh2+bh2)-pos;
//                       y'=x@Wfx + pos.Wrel  -> bf16)
__global__ __launch_bounds__(256) void hy_kernel(
    const float* __restrict__ x, const ushort* __restrict__ WT,
    const float* __restrict__ bh1, const float* __restrict__ Wh2,
    const float* __restrict__ bh2, const float* __restrict__ Wf,
    const float* __restrict__ pos, float* __restrict__ q,
    ushort* __restrict__ yb, int M)
{
    __shared__ ushort Bs[128 * 136];   // 34816 B
    __shared__ ushort yS[64 * 128];    // 16384 B  (51200 total -> 3 blocks/CU)
    const int tid = threadIdx.x;
    const int w = tid >> 6, L = tid & 63, qd = L >> 4, ln = L & 15;
    const int row0 = blockIdx.x * 64;
    const int arow = row0 + w * 16 + ln;

    // A fragments straight from global x, hi/lo split in regs
    short8 ah[4], al[4];
    {
        const float* base = x + (size_t)((arow < M) ? arow : 0) * 128 + qd * 8;
        float vb[8];
#pragma unroll
        for (int ks = 0; ks < 4; ++ks) {
            float4 v0 = make_float4(0.f, 0.f, 0.f, 0.f), v1 = v0;
            if (arow < M) {
                v0 = *(const float4*)(base + ks * 32);
                v1 = *(const float4*)(base + ks * 32 + 4);
            }
            vb[0] = v0.x; vb[1] = v0.y; vb[2] = v0.z; vb[3] = v0.w;
            vb[4] = v1.x; vb[5] = v1.y; vb[6] = v1.z; vb[7] = v1.w;
            split8(vb, ah[ks], al[ks]);
        }
    }

    STAGE_B(WT);                        // Wh1T
    __syncthreads();
    f32x4 acc1[8];
#pragma unroll
    for (int nt = 0; nt < 8; ++nt) acc1[nt] = (f32x4){0.f, 0.f, 0.f, 0.f};
    GEMM_CORE_REG(acc1, ah, al);
    __syncthreads();

    STAGE_B(WT + 16384);                // WfxT
    __syncthreads();
    f32x4 acc2[8];
#pragma unroll
    for (int nt = 0; nt < 8; ++nt) acc2[nt] = (f32x4){0.f, 0.f, 0.f, 0.f};
    GEMM_CORE_REG(acc2, ah, al);
    __syncthreads();

    // h1 (f32) into Bs region; y' (bf16) into yS
    float* h1s = (float*)Bs;   // 64 x 132 f32 = 33792 B
#pragma unroll
    for (int nt = 0; nt < 8; ++nt) {
        int n = nt * 16 + ln;
        float bias = bh1[n];
#pragma unroll
        for (int r = 0; r < 4; ++r)
            h1s[(w * 16 + qd * 4 + r) * 132 + n] = lrelu(acc1[nt][r] + bias);
    }
#pragma unroll
    for (int r = 0; r < 4; ++r) {
        int m = w * 16 + qd * 4 + r;
        int gm = row0 + m;
        float p0 = 0.f, p1 = 0.f, p2 = 0.f;
        if (gm < M) { p0 = pos[gm * 3]; p1 = pos[gm * 3 + 1]; p2 = pos[gm * 3 + 2]; }
#pragma unroll
        for (int nt = 0; nt < 8; ++nt) {
            int n = nt * 16 + ln;
            yS[m * 128 + n] = f2b(acc2[nt][r] + p0 * Wf[n] + p1 * Wf[128 + n] + p2 * Wf[256 + n]);
        }
    }
    __syncthreads();

    // q reduction (threads 0..191)
    int row = tid & 63, cc = tid >> 6;
    if (cc < 3 && row0 + row < M) {
        float s = 0.f;
#pragma unroll
        for (int k4 = 0; k4 < 32; ++k4) {
            float4 h = *(const float4*)&h1s[row * 132 + k4 * 4];
            s += h.x * Wh2[(k4 * 4 + 0) * 3 + cc] + h.y * Wh2[(k4 * 4 + 1) * 3 + cc]
               + h.z * Wh2[(k4 * 4 + 2) * 3 + cc] + h.w * Wh2[(k4 * 4 + 3) * 3 + cc];
        }
        q[(row0 + row) * 3 + cc] = tanhf(s + bh2[cc]) - pos[(row0 + row) * 3 + cc];
    }
    // y' copy-out: 1024 x 16B chunks
#pragma unroll
    for (int i = 0; i < 4; ++i) {
        int c = tid + 256 * i;
        int r = c >> 4, col8 = (c & 15) * 8;
        if (row0 + r < M)
            *(uint4*)(yb + (size_t)(row0 + r) * 128 + col8) = *(const uint4*)&yS[r * 128 + col8];
    }
}

// ---- dispatch 2: scatter aggregation via sortable-uint atomicMax -----------
// One wave per edge per iteration: 64 lanes read the 256 B y' row coalesced
// (wave-uniform edge index -> broadcast ei loads), then 2 fire-and-forget
// global atomicMax per lane into the f32-sortable agg plane. max commutes
// with the dst-dependent lrelu shift, so aggregating y' is exact.
__global__ __launch_bounds__(256) void edge_aggmax_kernel(
    const int* __restrict__ ei, const uint* __restrict__ ybu,
    uint* __restrict__ aggU, int E)
{
    const int widx = blockIdx.x * 4 + (threadIdx.x >> 6);
    const int lane = threadIdx.x & 63;
    const int W = gridDim.x * 4;
#pragma unroll 4
    for (int e = widx; e < E; e += W) {
        int src = ei[e];
        int dst = ei[E + e];
        uint u = ybu[(size_t)src * 64 + lane];
        uint slo = sortable(u << 16);
        uint shi = sortable(u & 0xFFFF0000u);
        atomicMax(&aggU[(size_t)dst * 128 + 2 * lane], slo);
        atomicMax(&aggU[(size_t)dst * 128 + 2 * lane + 1], shi);
    }
}

// ---- dispatch 3: decode(aggU) @ Wg1 -> lrelu -> @ Wg2 + bg2 + x -------------
// mid stored as single bf16 (LDS 52224 B -> 3 blocks/CU); GEMM2 single-MFMA.
__global__ __launch_bounds__(256) void midout_kernel(
    const uint* __restrict__ aggU, const float* __restrict__ qv,
    const float* __restrict__ Wf, const float* __restrict__ bfv,
    const ushort* __restrict__ Wg1T, const float* __restrict__ bg1,
    const ushort* __restrict__ Wg2T, const float* __restrict__ bg2,
    const float* __restrict__ x, float* __restrict__ out, int M)
{
    __shared__ ushort Bs[128 * 136];   // 34816 B
    __shared__ ushort Ms[64 * 136];    // 17408 B (52224 total -> 3 blocks/CU)
    const int tid = threadIdx.x;
    const int w = tid >> 6, L = tid & 63, qd = L >> 4, ln = L & 15;
    const int row0 = blockIdx.x * 64;
    const int arow = row0 + w * 16 + ln;

    // A fragments: load sortable-uint agg row, decode, split in regs
    short8 ah[4], al[4];
    {
        bool ok = arow < M;
        const uint* base = aggU + (size_t)(ok ? arow : 0) * 128 + qd * 8;
        float q0 = 0.f, q1 = 0.f, q2 = 0.f;
        if (ok) { q0 = qv[arow * 3]; q1 = qv[arow * 3 + 1]; q2 = qv[arow * 3 + 2]; }
        float vb[8];
        uint4 sent = make_uint4(S_EMPTY, S_EMPTY, S_EMPTY, S_EMPTY);
#pragma unroll
        for (int ks = 0; ks < 4; ++ks) {
            union { uint4 v[2]; uint s[8]; } a;
            a.v[0] = ok ? *(const uint4*)(base + ks * 32) : sent;
            a.v[1] = ok ? *(const uint4*)(base + ks * 32 + 4) : sent;
#pragma unroll
            for (int j = 0; j < 8; ++j) {
                int k = ks * 32 + qd * 8 + j;
                float dec = 0.f;
                uint s = a.s[j];
                if (s != S_EMPTY) {   // empty segment -> 0 (matches isfinite mask)
                    uint u = (s & 0x80000000u) ? (s ^ 0x80000000u) : ~s;
                    dec = lrelu(__uint_as_float(u)
                                + q0 * Wf[k] + q1 * Wf[128 + k] + q2 * Wf[256 + k] + bfv[k]);
                }
                vb[j] = dec;
            }
            split8(vb, ah[ks], al[ks]);
        }
    }

    STAGE_B(Wg1T);
    __syncthreads();
    f32x4 macc[8];
#pragma unroll
    for (int nt = 0; nt < 8; ++nt) macc[nt] = (f32x4){0.f, 0.f, 0.f, 0.f};
    GEMM_CORE_REG(macc, ah, al);
    __syncthreads();   // all waves done reading Bs (Wg1T)

    // mid (bf16) -> Ms; restage Bs = Wg2T
#pragma unroll
    for (int nt = 0; nt < 8; ++nt) {
        int n = nt * 16 + ln;
        float bias = bg1[n];
#pragma unroll
        for (int r = 0; r < 4; ++r)
            Ms[(w * 16 + qd * 4 + r) * 136 + n] = f2b(lrelu(macc[nt][r] + bias));
    }
    STAGE_B(Wg2T);
    __syncthreads();

    // second A fragments from Ms (bf16, single precision path)
    short8 a2[4];
#pragma unroll
    for (int ks = 0; ks < 4; ++ks)
        a2[ks] = *(const short8*)&Ms[(w * 16 + ln) * 136 + ks * 32 + qd * 8];

    f32x4 acc2[8];
#pragma unroll
    for (int nt = 0; nt < 8; ++nt) acc2[nt] = (f32x4){0.f, 0.f, 0.f, 0.f};
#pragma unroll
    for (int ks = 0; ks < 4; ++ks) {
#pragma unroll
        for (int nt = 0; nt < 8; ++nt) {
            short8 bfr = *(const short8*)&Bs[(nt * 16 + ln) * 136 + ks * 32 + qd * 8];
            acc2[nt] = __builtin_amdgcn_mfma_f32_16x16x32_bf16(a2[ks], bfr, acc2[nt], 0, 0, 0);
        }
    }
    __syncthreads();   // done reading Bs (Wg2T) and Ms

    // raw acc -> Bs region (f32 64x132); bg2 + x folded into coalesced copy-out
    float* outS = (float*)Bs;
#pragma unroll
    for (int r = 0; r < 4; ++r) {
        int m = w * 16 + qd * 4 + r;
#pragma unroll
        for (int nt = 0; nt < 8; ++nt)
            outS[m * 132 + nt * 16 + ln] = acc2[nt][r];
    }
    __syncthreads();
#pragma unroll
    for (int i = 0; i < 8; ++i) {
        int c = tid + 256 * i;
        int r = c >> 5, col4 = (c & 31) * 4;
        int gr = row0 + r;
        if (gr < M) {
            float4 o = *(const float4*)&outS[r * 132 + col4];
            float4 bv = *(const float4*)(bg2 + col4);
            float4 xv = *(const float4*)(x + (size_t)gr * 128 + col4);
            o.x += bv.x + xv.x; o.y += bv.y + xv.y;
            o.z += bv.z + xv.z; o.w += bv.w + xv.w;
            *(float4*)(out + (size_t)gr * 128 + col4) = o;
        }
    }
}

extern "C" void kernel_launch(void* const* d_in, const int* in_sizes, int n_in,
                              void* d_out, int out_size, void* d_ws, size_t ws_size,
                              hipStream_t stream)
{
    const float* x   = (const float*)d_in[0];
    const float* pos = (const float*)d_in[1];
    const int*   ei  = (const int*)d_in[2];
    const float* Wh1 = (const float*)d_in[3];
    const float* bh1 = (const float*)d_in[4];
    const float* Wh2 = (const float*)d_in[5];
    const float* bh2 = (const float*)d_in[6];
    const float* Wf  = (const float*)d_in[7];
    const float* bf  = (const float*)d_in[8];
    const float* Wg1 = (const float*)d_in[9];
    const float* bg1 = (const float*)d_in[10];
    const float* Wg2 = (const float*)d_in[11];
    const float* bg2 = (const float*)d_in[12];
    float* out = (float*)d_out;

    const int M = in_sizes[0] / 128;   // 50000
    const int E = in_sizes[2] / 2;     // 800000

    char* ws = (char*)d_ws;
    size_t off = 0;
    auto alloc = [&](size_t bytes) { void* p = ws + off; off += (bytes + 255) & ~255ull; return p; };
    ushort* yb   = (ushort*)alloc((size_t)M * 128 * sizeof(ushort));
    uint*   aggU = (uint*)alloc((size_t)M * 128 * sizeof(uint));
    ushort* WT   = (ushort*)alloc(4 * 16384 * sizeof(ushort));   // Wh1T,WfxT,Wg1T,Wg2T
    float*  q    = (float*)alloc((size_t)M * 3 * sizeof(float));

    const int gb = (M + 63) / 64;       // 782

    // dispatch 0: weight transpose + agg plane sentinel init
    wprep_kernel<<<256, 256, 0, stream>>>(Wh1, Wf, Wg1, Wg2, WT, aggU, M);
    // dispatch 1: hy (x-side MLP + per-node y' rows)
    hy_kernel<<<gb, 256, 0, stream>>>(x, WT, bh1, Wh2, bh2, Wf, pos, q, yb, M);
    // dispatch 2: scatter-atomicMax aggregation (no CSR at all)
    edge_aggmax_kernel<<<12500, 256, 0, stream>>>(ei, (const uint*)yb, aggU, E);
    // dispatch 3: decode + mlp_g + residual
    midout_kernel<<<gb, 256, 0, stream>>>(aggU, q, Wf, bf,
                                          WT + 2 * 16384, bg1,
                                          WT + 3 * 16384, bg2, x, out, M);
}

// Round 10
// 206.633 us; speedup vs baseline: 3.2811x; 3.2811x over previous
//
#include <hip/hip_runtime.h>
#include <cfloat>
#include <cmath>

#define NEG_SLOPE 0.01f

typedef __attribute__((ext_vector_type(8))) short short8;
typedef __attribute__((ext_vector_type(4))) float f32x4;

__device__ __forceinline__ float lrelu(float v) { return v >= 0.0f ? v : NEG_SLOPE * v; }

// f32 -> bf16 round-to-nearest-even (monotone; identity on exact bf16 values)
__device__ __forceinline__ ushort f2b(float f) {
    unsigned u = __float_as_uint(f);
    u += 0x7fffu + ((u >> 16) & 1u);
    return (ushort)(u >> 16);
}
__device__ __forceinline__ float b2f(ushort s) { return __uint_as_float(((unsigned)s) << 16); }

// split 8 consecutive f32 into hi/lo bf16 fragments (register-resident)
__device__ __forceinline__ void split8(const float* v, short8& hi, short8& lo) {
#pragma unroll
    for (int j = 0; j < 8; ++j) {
        ushort h = f2b(v[j]);
        hi[j] = (short)h;
        lo[j] = (short)f2b(v[j] - b2f(h));
    }
}

// ---- dispatch 0: bucket histogram (block-major G) + all-4-weight transpose --
// grid MUST be exactly 256 blocks x 256 threads.
// WT[mat][n*128+k]; mat 0=Wh1, 1=Wfx (Wf rows 3..130), 2=Wg1, 3=Wg2.
__global__ __launch_bounds__(256) void count_wprep_kernel(
    const int* __restrict__ ei, int* __restrict__ G, int E,
    const float* __restrict__ Wh1, const float* __restrict__ Wf,
    const float* __restrict__ Wg1, const float* __restrict__ Wg2,
    ushort* __restrict__ WT)
{
    __shared__ int cnt[256];
    const int t = threadIdx.x;
    const int b = blockIdx.x;

    // weight prep: exactly 4*16384 = 65536 entries over 256x256 threads
    {
        int tt = b * 256 + t;
        int mat = tt >> 14;
        int idx = tt & 16383;
        int n = idx >> 7, k = idx & 127;
        float v;
        if (mat == 0)      v = Wh1[k * 128 + n];
        else if (mat == 1) v = Wf[(k + 3) * 128 + n];
        else if (mat == 2) v = Wg1[k * 128 + n];
        else               v = Wg2[k * 128 + n];
        WT[(tt - idx) + n * 128 + k] = f2b(v);
    }

    cnt[t] = 0;
    __syncthreads();
    for (int e = b * 256 + t; e < E; e += 65536)
        atomicAdd(&cnt[ei[E + e] >> 8], 1);
    __syncthreads();
    G[b * 256 + t] = cnt[t];           // block-major, coalesced
}

// ---------------- MFMA GEMM skeleton ----------------
// block = 256 thr = 4 waves; tile 64 rows x 128 cols; K = 128 (4 steps of 32).
// wave w covers rows [w*16, w*16+16); lane: qd = L>>4, ln = L&15.
// A-operand in registers (hi/lo split, 2 MFMAs per fragment).
// b_frag: Bs[n = nt*16+ln][k = ks*32+qd*8+j]  (LDS, stride 136 bf16)
// D:      C[m = w*16+qd*4+r][n = nt*16+ln] = acc[nt][r]

#define GEMM_CORE_REG(ACC, AH, AL)                                              \
    {                                                                           \
        _Pragma("unroll")                                                       \
        for (int ks = 0; ks < 4; ++ks) {                                        \
            _Pragma("unroll")                                                   \
            for (int nt = 0; nt < 8; ++nt) {                                    \
                short8 bfr = *(const short8*)&Bs[(nt * 16 + ln) * 136 + ks * 32 + qd * 8]; \
                ACC[nt] = __builtin_amdgcn_mfma_f32_16x16x32_bf16(AL[ks], bfr, ACC[nt], 0, 0, 0); \
                ACC[nt] = __builtin_amdgcn_mfma_f32_16x16x32_bf16(AH[ks], bfr, ACC[nt], 0, 0, 0); \
            }                                                                   \
        }                                                                       \
    }

// stage B from pre-transposed bf16 WT (layout WT[n*128+k]); coalesced uint4
#define STAGE_B(WTP)                                                            \
    {                                                                           \
        _Pragma("unroll")                                                       \
        for (int i = 0; i < 8; ++i) {                                           \
            int c = tid + 256 * i;                                              \
            int r = c >> 4, col8 = (c & 15) * 8;                                \
            *(uint4*)&Bs[r * 136 + col8] = *(const uint4*)((WTP) + r * 128 + col8); \
        }                                                                       \
    }

// ---- fused dispatch 1: blocks [0, GB) = hy role; [GB, GB+256) = scan+partition.
// hy (register-epilogue version, LDS = Bs only -> 4 blocks/CU):
//   h1 = lrelu(x@Wh1+bh1) stays in acc1 regs; q-reduction via 16-lane butterfly;
//   y' = x@Wfx + pos.Wrel packed to bf16 via lane-pair shfl, stored direct.
__global__ __launch_bounds__(256, 4) void hy_scanpart_kernel(
    const int* __restrict__ ei, const int* __restrict__ G,
    int* __restrict__ bbase, uint* __restrict__ bpairs, int E, int GB,
    const float* __restrict__ x, const ushort* __restrict__ WT,
    const float* __restrict__ bh1, const float* __restrict__ Wh2,
    const float* __restrict__ bh2, const float* __restrict__ Wf,
    const float* __restrict__ pos, float* __restrict__ q,
    ushort* __restrict__ yb, int M)
{
    __shared__ ushort Bs[128 * 136];   // 34816 B
    __shared__ int sp[512];            // 2048 B scanpart scratch (36864 total -> 4 blocks/CU)
    const int tid = threadIdx.x;

    if (blockIdx.x >= GB) {
        // ---------- scan + partition role ----------
        int* s   = sp;                 // [256]
        int* cur = sp + 256;           // [256]
        const int b = blockIdx.x - GB;
        const int t = tid;

        int cs = 0, pp = 0;
        for (int bb = 0; bb < 256; ++bb) {
            int v = G[bb * 256 + t];   // coalesced: lanes t consecutive
            if (bb < b) pp += v;
            cs += v;
        }
        s[t] = cs;
        __syncthreads();
        for (int d = 1; d < 256; d <<= 1) {
            int a = (t >= d) ? s[t - d] : 0;
            __syncthreads();
            s[t] += a;
            __syncthreads();
        }
        int colbase = s[t] - cs;
        cur[t] = colbase + pp;
        if (b == 0) {
            bbase[t] = colbase;
            if (t == 255) bbase[256] = colbase + cs;   // = E
        }
        __syncthreads();

        for (int e = b * 256 + t; e < E; e += 65536) {
            int src = ei[e];
            int dst = ei[E + e];
            int p = atomicAdd(&cur[dst >> 8], 1);
            bpairs[p] = (uint)src | ((uint)(dst & 255) << 24);
        }
        return;
    }

    // ---------- hy role ----------
    const int w = tid >> 6, L = tid & 63, qd = L >> 4, ln = L & 15;
    const int row0 = blockIdx.x * 64;
    const int arow = row0 + w * 16 + ln;

    // A fragments straight from global x, hi/lo split in regs
    short8 ah[4], al[4];
    {
        const float* base = x + (size_t)((arow < M) ? arow : 0) * 128 + qd * 8;
        float vb[8];
#pragma unroll
        for (int ks = 0; ks < 4; ++ks) {
            float4 v0 = make_float4(0.f, 0.f, 0.f, 0.f), v1 = v0;
            if (arow < M) {
                v0 = *(const float4*)(base + ks * 32);
                v1 = *(const float4*)(base + ks * 32 + 4);
            }
            vb[0] = v0.x; vb[1] = v0.y; vb[2] = v0.z; vb[3] = v0.w;
            vb[4] = v1.x; vb[5] = v1.y; vb[6] = v1.z; vb[7] = v1.w;
            split8(vb, ah[ks], al[ks]);
        }
    }

    STAGE_B(WT);                        // Wh1T
    __syncthreads();
    f32x4 acc1[8];
#pragma unroll
    for (int nt = 0; nt < 8; ++nt) acc1[nt] = (f32x4){0.f, 0.f, 0.f, 0.f};
    GEMM_CORE_REG(acc1, ah, al);
    __syncthreads();

    STAGE_B(WT + 16384);                // WfxT
    __syncthreads();
    f32x4 acc2[8];
#pragma unroll
    for (int nt = 0; nt < 8; ++nt) acc2[nt] = (f32x4){0.f, 0.f, 0.f, 0.f};
    GEMM_CORE_REG(acc2, ah, al);
    // no further LDS use -> no barrier; epilogue is pure-register

    // ---- q partials from acc1 (acc1 dies here) ----
    float qa0[4], qa1[4], qa2[4];
#pragma unroll
    for (int r = 0; r < 4; ++r) { qa0[r] = 0.f; qa1[r] = 0.f; qa2[r] = 0.f; }
#pragma unroll
    for (int nt = 0; nt < 8; ++nt) {
        int nn = nt * 16 + ln;
        float bias = bh1[nn];
        float w0 = Wh2[nn * 3], w1 = Wh2[nn * 3 + 1], w2 = Wh2[nn * 3 + 2];
#pragma unroll
        for (int r = 0; r < 4; ++r) {
            float h = lrelu(acc1[nt][r] + bias);
            qa0[r] += h * w0; qa1[r] += h * w1; qa2[r] += h * w2;
        }
    }

    // ---- y' direct store: lane-pair bf16 pack via shfl, even lanes write ----
#pragma unroll
    for (int r = 0; r < 4; ++r) {
        int gm = row0 + w * 16 + qd * 4 + r;
        float p0 = 0.f, p1 = 0.f, p2 = 0.f;
        if (gm < M) { p0 = pos[gm * 3]; p1 = pos[gm * 3 + 1]; p2 = pos[gm * 3 + 2]; }
#pragma unroll
        for (int nt = 0; nt < 8; ++nt) {
            int n = nt * 16 + ln;
            float val = acc2[nt][r] + p0 * Wf[n] + p1 * Wf[128 + n] + p2 * Wf[256 + n];
            float pv = __shfl_xor(val, 1);
            if (!(ln & 1) && gm < M) {
                uint u = (uint)f2b(val) | ((uint)f2b(pv) << 16);
                ((uint*)yb)[(size_t)gm * 64 + nt * 8 + (ln >> 1)] = u;
            }
        }
    }

    // ---- q finalize: 16-lane butterfly, 3 lanes apply tanh ----
#pragma unroll
    for (int r = 0; r < 4; ++r) {
#pragma unroll
        for (int d = 1; d < 16; d <<= 1) {
            qa0[r] += __shfl_xor(qa0[r], d);
            qa1[r] += __shfl_xor(qa1[r], d);
            qa2[r] += __shfl_xor(qa2[r], d);
        }
    }
#pragma unroll
    for (int r = 0; r < 4; ++r) {
        int gm = row0 + w * 16 + qd * 4 + r;
        if (ln < 3 && gm < M) {
            float sv = (ln == 0) ? qa0[r] : (ln == 1) ? qa1[r] : qa2[r];
            q[gm * 3 + ln] = tanhf(sv + bh2[ln]) - pos[gm * 3 + ln];
        }
    }
}

// ---- dispatch 2: per-bucket local CSR (deg -> scan -> scatter) ----
__global__ __launch_bounds__(256) void bucket_csr_kernel(
    const uint* __restrict__ bpairs, const int* __restrict__ bbase,
    int* __restrict__ offs, int* __restrict__ srcs, int E, int M, int NBK)
{
    __shared__ int deg[256], scn[256], cur[256];
    const int b = blockIdx.x;
    const int t = threadIdx.x;
    const int base = bbase[b];
    const int end  = bbase[b + 1];
    deg[t] = 0;
    __syncthreads();
    for (int p = base + t; p < end; p += 256)
        atomicAdd(&deg[bpairs[p] >> 24], 1);
    __syncthreads();
    scn[t] = deg[t];
    __syncthreads();
    for (int d = 1; d < 256; d <<= 1) {
        int a = (t >= d) ? scn[t - d] : 0;
        __syncthreads();
        scn[t] += a;
        __syncthreads();
    }
    int excl = scn[t] - deg[t];
    cur[t] = excl;
    int node = b * 256 + t;
    if (node < M) offs[node] = base + excl;
    if (node == M - 1 || (b == NBK - 1 && t == 255)) offs[M] = E;
    __syncthreads();
    for (int p = base + t; p < end; p += 256) {
        uint pk = bpairs[p];
        int qpos = atomicAdd(&cur[pk >> 24], 1);
        srcs[base + qpos] = (int)(pk & 0xFFFFFFu);
    }
}

// ---- aggregation: agg[i,:] = max over incoming srcs of y'[s,:] (bf16) -------
// one wave per node; 12500 blocks, no LDS -> max occupancy, deep MLP.
__global__ __launch_bounds__(256) void agg_kernel(
    const int* __restrict__ offs, const int* __restrict__ srcs,
    const ushort* __restrict__ yb, ushort* __restrict__ aggb, int M)
{
    int wave = threadIdx.x >> 6;
    int lane = threadIdx.x & 63;
    int node = blockIdx.x * 4 + wave;
    if (node >= M) return;
    int o0 = offs[node], o1 = offs[node + 1];
    float a0 = -INFINITY, a1 = -INFINITY;
    const uint* yp = (const uint*)yb;
    int j = o0;
    for (; j + 7 < o1; j += 8) {
        uint u[8];
#pragma unroll
        for (int t = 0; t < 8; ++t)
            u[t] = yp[(size_t)srcs[j + t] * 64 + lane];
#pragma unroll
        for (int t = 0; t < 8; ++t) {
            a0 = fmaxf(a0, __uint_as_float(u[t] << 16));
            a1 = fmaxf(a1, __uint_as_float(u[t] & 0xFFFF0000u));
        }
    }
    for (; j + 3 < o1; j += 4) {
        uint u[4];
#pragma unroll
        for (int t = 0; t < 4; ++t)
            u[t] = yp[(size_t)srcs[j + t] * 64 + lane];
#pragma unroll
        for (int t = 0; t < 4; ++t) {
            a0 = fmaxf(a0, __uint_as_float(u[t] << 16));
            a1 = fmaxf(a1, __uint_as_float(u[t] & 0xFFFF0000u));
        }
    }
    for (; j < o1; ++j) {
        uint u = yp[(size_t)srcs[j] * 64 + lane];
        a0 = fmaxf(a0, __uint_as_float(u << 16));
        a1 = fmaxf(a1, __uint_as_float(u & 0xFFFF0000u));
    }
    // values are exact bf16 (or -inf) -> repack without rounding
    uint pk = (__float_as_uint(a0) >> 16) | (__float_as_uint(a1) & 0xFFFF0000u);
    ((uint*)aggb)[(size_t)node * 64 + lane] = pk;
}

// ---- fused: decode(agg) @ Wg1 -> lrelu -> @ Wg2 + bg2 + x -------------------
// mid stored as single bf16 (LDS 52224 B -> 3 blocks/CU); GEMM2 single-MFMA.
__global__ __launch_bounds__(256) void midout_kernel(
    const ushort* __restrict__ aggb, const float* __restrict__ qv,
    const float* __restrict__ Wf, const float* __restrict__ bfv,
    const ushort* __restrict__ Wg1T, const float* __restrict__ bg1,
    const ushort* __restrict__ Wg2T, const float* __restrict__ bg2,
    const float* __restrict__ x, float* __restrict__ out, int M)
{
    __shared__ ushort Bs[128 * 136];   // 34816 B
    __shared__ ushort Ms[64 * 136];    // 17408 B (52224 total -> 3 blocks/CU)
    const int tid = threadIdx.x;
    const int w = tid >> 6, L = tid & 63, qd = L >> 4, ln = L & 15;
    const int row0 = blockIdx.x * 64;
    const int arow = row0 + w * 16 + ln;

    // A fragments: load agg bf16 row, decode, split in regs
    short8 ah[4], al[4];
    {
        bool ok = arow < M;
        const ushort* base = aggb + (size_t)(ok ? arow : 0) * 128 + qd * 8;
        float q0 = 0.f, q1 = 0.f, q2 = 0.f;
        if (ok) { q0 = qv[arow * 3]; q1 = qv[arow * 3 + 1]; q2 = qv[arow * 3 + 2]; }
        float vb[8];
#pragma unroll
        for (int ks = 0; ks < 4; ++ks) {
            union { uint4 u; ushort s[8]; } a;
            a.u = ok ? *(const uint4*)(base + ks * 32) : make_uint4(0xFF80FF80u, 0xFF80FF80u, 0xFF80FF80u, 0xFF80FF80u);
#pragma unroll
            for (int j = 0; j < 8; ++j) {
                int k = ks * 32 + qd * 8 + j;
                float dec = 0.f;
                if (a.s[j] != 0xFF80u)   // bf16 -inf sentinel = empty segment
                    dec = lrelu(b2f(a.s[j]) + q0 * Wf[k] + q1 * Wf[128 + k] + q2 * Wf[256 + k] + bfv[k]);
                vb[j] = dec;
            }
            split8(vb, ah[ks], al[ks]);
        }
    }

    STAGE_B(Wg1T);
    __syncthreads();
    f32x4 macc[8];
#pragma unroll
    for (int nt = 0; nt < 8; ++nt) macc[nt] = (f32x4){0.f, 0.f, 0.f, 0.f};
    GEMM_CORE_REG(macc, ah, al);
    __syncthreads();   // all waves done reading Bs (Wg1T)

    // mid (bf16) -> Ms; restage Bs = Wg2T
#pragma unroll
    for (int nt = 0; nt < 8; ++nt) {
        int n = nt * 16 + ln;
        float bias = bg1[n];
#pragma unroll
        for (int r = 0; r < 4; ++r)
            Ms[(w * 16 + qd * 4 + r) * 136 + n] = f2b(lrelu(macc[nt][r] + bias));
    }
    STAGE_B(Wg2T);
    __syncthreads();

    // second A fragments from Ms (bf16, single precision path)
    short8 a2[4];
#pragma unroll
    for (int ks = 0; ks < 4; ++ks)
        a2[ks] = *(const short8*)&Ms[(w * 16 + ln) * 136 + ks * 32 + qd * 8];

    f32x4 acc2[8];
#pragma unroll
    for (int nt = 0; nt < 8; ++nt) acc2[nt] = (f32x4){0.f, 0.f, 0.f, 0.f};
#pragma unroll
    for (int ks = 0; ks < 4; ++ks) {
#pragma unroll
        for (int nt = 0; nt < 8; ++nt) {
            short8 bfr = *(const short8*)&Bs[(nt * 16 + ln) * 136 + ks * 32 + qd * 8];
            acc2[nt] = __builtin_amdgcn_mfma_f32_16x16x32_bf16(a2[ks], bfr, acc2[nt], 0, 0, 0);
        }
    }
    __syncthreads();   // done reading Bs (Wg2T) and Ms

    // raw acc -> Bs region (f32 64x132); bg2 + x folded into coalesced copy-out
    float* outS = (float*)Bs;
#pragma unroll
    for (int r = 0; r < 4; ++r) {
        int m = w * 16 + qd * 4 + r;
#pragma unroll
        for (int nt = 0; nt < 8; ++nt)
            outS[m * 132 + nt * 16 + ln] = acc2[nt][r];
    }
    __syncthreads();
#pragma unroll
    for (int i = 0; i < 8; ++i) {
        int c = tid + 256 * i;
        int r = c >> 5, col4 = (c & 31) * 4;
        int gr = row0 + r;
        if (gr < M) {
            float4 o = *(const float4*)&outS[r * 132 + col4];
            float4 bv = *(const float4*)(bg2 + col4);
            float4 xv = *(const float4*)(x + (size_t)gr * 128 + col4);
            o.x += bv.x + xv.x; o.y += bv.y + xv.y;
            o.z += bv.z + xv.z; o.w += bv.w + xv.w;
            *(float4*)(out + (size_t)gr * 128 + col4) = o;
        }
    }
}

extern "C" void kernel_launch(void* const* d_in, const int* in_sizes, int n_in,
                              void* d_out, int out_size, void* d_ws, size_t ws_size,
                              hipStream_t stream)
{
    const float* x   = (const float*)d_in[0];
    const float* pos = (const float*)d_in[1];
    const int*   ei  = (const int*)d_in[2];
    const float* Wh1 = (const float*)d_in[3];
    const float* bh1 = (const float*)d_in[4];
    const float* Wh2 = (const float*)d_in[5];
    const float* bh2 = (const float*)d_in[6];
    const float* Wf  = (const float*)d_in[7];
    const float* bf  = (const float*)d_in[8];
    const float* Wg1 = (const float*)d_in[9];
    const float* bg1 = (const float*)d_in[10];
    const float* Wg2 = (const float*)d_in[11];
    const float* bg2 = (const float*)d_in[12];
    float* out = (float*)d_out;

    const int M = in_sizes[0] / 128;   // 50000
    const int E = in_sizes[2] / 2;     // 800000
    const int NBK = (M + 255) >> 8;    // 196 buckets of 256 nodes

    char* ws = (char*)d_ws;
    size_t off = 0;
    auto alloc = [&](size_t bytes) { void* p = ws + off; off += (bytes + 255) & ~255ull; return p; };
    ushort* yb     = (ushort*)alloc((size_t)M * 128 * sizeof(ushort));
    ushort* aggb   = (ushort*)alloc((size_t)M * 128 * sizeof(ushort));
    ushort* WT     = (ushort*)alloc(4 * 16384 * sizeof(ushort));   // Wh1T,WfxT,Wg1T,Wg2T
    float*  q      = (float*)alloc((size_t)M * 3 * sizeof(float));
    int*    offs   = (int*)alloc((size_t)(M + 1) * sizeof(int));
    int*    G      = (int*)alloc(256 * 256 * sizeof(int));         // block-major
    int*    bbase  = (int*)alloc(257 * sizeof(int));
    uint*   bpairs = (uint*)alloc((size_t)E * sizeof(uint));
    int*    srcs   = (int*)alloc((size_t)E * sizeof(int));

    const int gb = (M + 63) / 64;       // 782

    // dispatch 0: bucket histogram + all-weight transpose (256 blocks)
    count_wprep_kernel<<<256, 256, 0, stream>>>(ei, G, E, Wh1, Wf, Wg1, Wg2, WT);
    // dispatch 1: hy (blocks 0..gb-1) || scan+partition (blocks gb..gb+255)
    hy_scanpart_kernel<<<gb + 256, 256, 0, stream>>>(
        ei, G, bbase, bpairs, E, gb,
        x, WT, bh1, Wh2, bh2, Wf, pos, q, yb, M);
    // dispatch 2: per-bucket CSR
    bucket_csr_kernel<<<NBK, 256, 0, stream>>>(bpairs, bbase, offs, srcs, E, M, NBK);
    // dispatch 3: aggregation (high-occupancy standalone gather)
    agg_kernel<<<(M + 3) / 4, 256, 0, stream>>>(offs, srcs, yb, aggb, M);
    // dispatch 4: decode + mlp_g + residual
    midout_kernel<<<gb, 256, 0, stream>>>(aggb, q, Wf, bf,
                                          WT + 2 * 16384, bg1,
                                          WT + 3 * 16384, bg2, x, out, M);
}